// Round 1
// baseline (42.463 us; speedup 1.0000x reference)
//
#include <hip/hip_runtime.h>

// QuantumLayer: boson-sampling distribution + linear head.
//   x:[512,8] f32, thetas:[12] f32, W:[4368,10] f32, b:[10] f32 -> out:[512,10] f32
// Key identities used:
//   * U is built by left-multiplying row-ops => columns evolve independently;
//     only columns 0..4 are needed (Ucols).
//   * Permanent via Glynn's formula (16 terms) instead of Ryser (32 masks):
//       perm(A) = 2^{1-n} sum_{delta, d0=+1} (prod delta) prod_i (sum_j delta_j a_ij)
//     sign folded into rs (sign^5 == sign), 2^-4 prefactor folded into the norm.

#define MODES 12
#define NPH   5
#define KG    16        // 2^(NPH-1) Glynn terms
#define S_TOT 4368      // C(16,5)
#define TPB   256
#define NOUT  10

#define TWO_PI_F 6.28318530717958647692f
#define RS2      0.70710678118654752440f

__device__ __forceinline__ int binom_small(int n, int r) {
  // C(n,r), r<=4, exact stepwise (p stays C(n,i))
  int p = 1;
  for (int i = 0; i < r; ++i) p = p * (n - i) / (i + 1);
  return p;
}

// rank -> nibble-packed non-decreasing 5-tuple (m0..m4), lex order of
// itertools.combinations_with_replacement(range(12), 5)
__device__ unsigned unrank5(int rank) {
  unsigned code = 0;
  int prev = 0;
  for (int pos = 0; pos < 5; ++pos) {
    int L = 5 - pos;              // remaining positions incl. this one
    int v = prev;
    for (; v < 11; ++v) {
      int c2 = binom_small(12 - v + L - 2, L - 1); // #seqs starting with v
      if (rank < c2) break;
      rank -= c2;
    }
    code = (code << 4) | (unsigned)v;
    prev = v;
  }
  return code;
}

// lex successor of a packed 5-multiset code
__device__ __forceinline__ unsigned next_code(unsigned c) {
  if ((c & 15u) < 11u) return c + 1u;
  unsigned m3 = (c >> 4) & 15u;
  if (m3 < 11u) { unsigned nv = m3 + 1u; return (c & 0xFFF00u) | (nv << 4) | nv; }
  unsigned m2 = (c >> 8) & 15u;
  if (m2 < 11u) { unsigned nv = m2 + 1u; return (c & 0xFF000u) | (nv << 8) | (nv << 4) | nv; }
  unsigned m1 = (c >> 12) & 15u;
  if (m1 < 11u) { unsigned nv = m1 + 1u; return (c & 0xF0000u) | (nv << 12) | (nv << 8) | (nv << 4) | nv; }
  unsigned nv = ((c >> 16) & 15u) + 1u;
  return (nv << 16) | (nv << 12) | (nv << 8) | (nv << 4) | nv;
}

#define BFLY(i, j)                                                 \
  { float ar = ur[i], ai = ui[i], br = ur[j], bi = ui[j];          \
    ur[i] = RS2 * (ar - bi); ui[i] = RS2 * (ai + br);              \
    ur[j] = RS2 * (br - ai); ui[j] = RS2 * (bi + ar); }

__global__ __launch_bounds__(TPB, 2) void qlayer_kernel(
    const float* __restrict__ x,      // [B,8]
    const float* __restrict__ th,     // [12]
    const float* __restrict__ W,      // [S_TOT,10]
    const float* __restrict__ bias,   // [10]
    float* __restrict__ out)          // [B,10]
{
  __shared__ float2 rs[KG][MODES];    // Glynn row-sums, sign pre-folded
  __shared__ float2 uc[MODES][NPH];   // Ucols staging
  __shared__ float  wred[4][NOUT];    // per-wave partials

  const int b = blockIdx.x;
  const int t = threadIdx.x;

  // ---------- Phase A: evolve columns 0..4 of U (threads 0..4) ----------
  if (t < NPH) {
    float ur[MODES], ui[MODES];
    #pragma unroll
    for (int m = 0; m < MODES; ++m) { ur[m] = 0.f; ui[m] = 0.f; }
    ur[t] = 1.f;

    #pragma unroll
    for (int k = 0; k < 20; ++k) {
      const int mode = k % MODES;     // compile-time (k unrolled)
      float phi = (k < 12) ? th[k] : x[b * 8 + (k - 12)] * TWO_PI_F;
      float sp, cp;
      sincosf(phi, &sp, &cp);
      // u[mode] *= exp(i*phi)
      float re = ur[mode] * cp - ui[mode] * sp;
      float im = ur[mode] * sp + ui[mode] * cp;
      ur[mode] = re; ui[mode] = im;
      if ((k & 1) == 0) {             // BS_EVEN: (0,1)(2,3)...(10,11)
        BFLY(0, 1) BFLY(2, 3) BFLY(4, 5) BFLY(6, 7) BFLY(8, 9) BFLY(10, 11)
      } else {                        // BS_ODD: (1,2)(3,4)...(9,10)
        BFLY(1, 2) BFLY(3, 4) BFLY(5, 6) BFLY(7, 8) BFLY(9, 10)
      }
    }
    #pragma unroll
    for (int m = 0; m < MODES; ++m) uc[m][t] = make_float2(ur[m], ui[m]);
  }
  __syncthreads();

  // ---------- Phase B: rs[k][m] = sign_k * sum_c delta_c(k) * Ucols[m][c] ----------
  if (t < KG * MODES) {
    const int k = t / MODES;
    const int m = t - k * MODES;
    float sre = uc[m][0].x, sim = uc[m][0].y;   // delta_0 = +1 fixed
    #pragma unroll
    for (int c = 1; c < NPH; ++c) {
      float d = ((k >> (c - 1)) & 1) ? -1.f : 1.f;
      sre = fmaf(d, uc[m][c].x, sre);
      sim = fmaf(d, uc[m][c].y, sim);
    }
    float sg = (__popc((unsigned)k) & 1) ? -1.f : 1.f;  // sign^5 == sign
    rs[k][m] = make_float2(sg * sre, sg * sim);
  }
  __syncthreads();

  // ---------- Phase C: permanents + probs + W accumulation ----------
  // thread t owns s in [lo, lo+cnt): first 16 threads take 18, rest 17 (16*18+240*17=4368)
  const int cnt = (t < 16) ? 18 : 17;
  const int lo  = (t < 16) ? t * 18 : 288 + (t - 16) * 17;

  float po[NOUT];
  #pragma unroll
  for (int o = 0; o < NOUT; ++o) po[o] = 0.f;

  unsigned code = unrank5(lo);
  for (int ii = 0; ii < cnt; ++ii) {
    const int s  = lo + ii;
    const int m0 = (code >> 16) & 15, m1 = (code >> 12) & 15;
    const int m2 = (code >> 8)  & 15, m3 = (code >> 4)  & 15;
    const int m4 =  code        & 15;

    float pr = 0.f, pi = 0.f;
    #pragma unroll
    for (int k = 0; k < KG; ++k) {
      float2 a  = rs[k][m0];
      float2 b2 = rs[k][m1];
      float2 c2 = rs[k][m2];
      float2 d2 = rs[k][m3];
      float2 e2 = rs[k][m4];
      float t1r = a.x * b2.x - a.y * b2.y;
      float t1i = a.x * b2.y + a.y * b2.x;
      float t2r = c2.x * d2.x - c2.y * d2.y;
      float t2i = c2.x * d2.y + c2.y * d2.x;
      float t3r = t1r * t2r - t1i * t2i;
      float t3i = t1r * t2i + t1i * t2r;
      pr += t3r * e2.x - t3i * e2.y;
      pi += t3r * e2.y + t3i * e2.x;
    }

    // NORM = prod over runs of (run length)!  (runs of equal m in sorted tuple)
    int run = 1, mult = 1;
    run = (m1 == m0) ? run + 1 : 1; mult *= run;
    run = (m2 == m1) ? run + 1 : 1; mult *= run;
    run = (m3 == m2) ? run + 1 : 1; mult *= run;
    run = (m4 == m3) ? run + 1 : 1; mult *= run;

    // Glynn prefactor 2^-4 squared -> 1/256
    float prob = (pr * pr + pi * pi) / (256.f * (float)mult);

    const float* wr = W + s * NOUT;
    #pragma unroll
    for (int o = 0; o < NOUT; ++o) po[o] = fmaf(prob, wr[o], po[o]);

    code = next_code(code);
  }

  // ---------- Phase D: block reduction, out[b][o] ----------
  #pragma unroll
  for (int o = 0; o < NOUT; ++o) {
    float v = po[o];
    #pragma unroll
    for (int off = 32; off > 0; off >>= 1) v += __shfl_down(v, off, 64);
    po[o] = v;
  }
  const int lane = t & 63, wave = t >> 6;
  if (lane == 0) {
    #pragma unroll
    for (int o = 0; o < NOUT; ++o) wred[wave][o] = po[o];
  }
  __syncthreads();
  if (t < NOUT) {
    out[b * NOUT + t] = wred[0][t] + wred[1][t] + wred[2][t] + wred[3][t] + bias[t];
  }
}

extern "C" void kernel_launch(void* const* d_in, const int* in_sizes, int n_in,
                              void* d_out, int out_size, void* d_ws, size_t ws_size,
                              hipStream_t stream) {
  (void)n_in; (void)out_size; (void)d_ws; (void)ws_size;
  const float* x    = (const float*)d_in[0];
  const float* th   = (const float*)d_in[1];
  const float* W    = (const float*)d_in[2];
  const float* bias = (const float*)d_in[3];
  float* out        = (float*)d_out;
  const int B = in_sizes[0] / 8;   // 512
  qlayer_kernel<<<B, TPB, 0, stream>>>(x, th, W, bias, out);
}